// Round 1
// baseline (16012.415 us; speedup 1.0000x reference)
//
#include <hip/hip_runtime.h>

typedef _Float16 f16;
typedef _Float16 half8 __attribute__((ext_vector_type(8)));
typedef _Float16 half4 __attribute__((ext_vector_type(4)));
typedef float f32x4 __attribute__((ext_vector_type(4)));

#define TT 512
#define NB 64
#define HID 1024
#define NL 4

// ---------------- prep: fp32->fp16 weights + inv_tau = 1/softplus(tau) ----------------
__global__ void prep_k(const float* __restrict__ Wih, const float* __restrict__ Whh,
                       const float* __restrict__ tau,
                       f16* __restrict__ WihH, f16* __restrict__ WhhH,
                       float* __restrict__ invTau) {
  size_t stride = (size_t)gridDim.x * blockDim.x;
  size_t i0 = (size_t)blockIdx.x * blockDim.x + threadIdx.x;
  const size_t n4 = (size_t)NL * 3072 * 1024 / 4;
  for (size_t i = i0; i < n4; i += stride) {
    f32x4 a = ((const f32x4*)Wih)[i];
    f32x4 b = ((const f32x4*)Whh)[i];
    half4 ha, hb;
    ha[0]=(f16)a[0]; ha[1]=(f16)a[1]; ha[2]=(f16)a[2]; ha[3]=(f16)a[3];
    hb[0]=(f16)b[0]; hb[1]=(f16)b[1]; hb[2]=(f16)b[2]; hb[3]=(f16)b[3];
    ((half4*)WihH)[i] = ha;
    ((half4*)WhhH)[i] = hb;
  }
  if (i0 < NL*HID) invTau[i0] = 1.0f / log1pf(expf(tau[i0]));
}

// ---------------- GX0 = x @ W_ih[0]^T  (no bias), stored [T][B][3072] f16 ----------------
// M=32768 (r = b*512+t), N=3072, K=1024.  128x128 tile, BK=64, 256 thr (4 waves, 2x2 of 64x64).
__global__ __launch_bounds__(256) void gx0_k(const float* __restrict__ x,
                                             const f16* __restrict__ W0,
                                             f16* __restrict__ GX0) {
  __shared__ char As[16384];
  __shared__ char Bs[16384];
  const int tid = threadIdx.x, lane = tid & 63, wv = tid >> 6;
  const int wr = wv >> 1, wc = wv & 1;
  const int r0 = blockIdx.x * 128, n0 = blockIdx.y * 128;
  f32x4 acc[4][4];
  #pragma unroll
  for (int m=0;m<4;m++)
    #pragma unroll
    for (int n=0;n<4;n++) acc[m][n] = (f32x4){0.f,0.f,0.f,0.f};

  f32x4 rx[4][2]; half8 rw[4];
  int rrow[4], rc8[4];
  #pragma unroll
  for (int j=0;j<4;j++) { int id = tid + 256*j; rrow[j] = id>>3; rc8[j] = (id&7)*8; }
  // prologue load chunk 0
  #pragma unroll
  for (int j=0;j<4;j++) {
    const float* sx = x + (size_t)(r0+rrow[j])*1024 + rc8[j];
    rx[j][0] = *(const f32x4*)sx; rx[j][1] = *(const f32x4*)(sx+4);
    rw[j] = *(const half8*)(W0 + (size_t)(n0+rrow[j])*1024 + rc8[j]);
  }
  for (int kc = 0; kc < 16; ++kc) {
    // store staged regs -> LDS (XOR swizzle within 128B row)
    #pragma unroll
    for (int j=0;j<4;j++) {
      half8 h;
      h[0]=(f16)rx[j][0][0]; h[1]=(f16)rx[j][0][1]; h[2]=(f16)rx[j][0][2]; h[3]=(f16)rx[j][0][3];
      h[4]=(f16)rx[j][1][0]; h[5]=(f16)rx[j][1][1]; h[6]=(f16)rx[j][1][2]; h[7]=(f16)rx[j][1][3];
      int off = rrow[j]*128 + ((rc8[j]*2) ^ ((rrow[j]&7)<<4));
      *(half8*)(As + off) = h;
      *(half8*)(Bs + off) = rw[j];
    }
    __syncthreads();
    if (kc < 15) {  // async prefetch next chunk while MFMAs run
      int k0 = (kc+1)*64;
      #pragma unroll
      for (int j=0;j<4;j++) {
        const float* sx = x + (size_t)(r0+rrow[j])*1024 + k0 + rc8[j];
        rx[j][0] = *(const f32x4*)sx; rx[j][1] = *(const f32x4*)(sx+4);
        rw[j] = *(const half8*)(W0 + (size_t)(n0+rrow[j])*1024 + k0 + rc8[j]);
      }
    }
    #pragma unroll
    for (int ks=0; ks<2; ++ks) {
      half8 aF[4], bF[4];
      int kb = ks*64 + ((lane>>4)&3)*16;
      #pragma unroll
      for (int m=0;m<4;m++) {
        int row = wr*64 + m*16 + (lane&15);
        aF[m] = *(const half8*)(As + row*128 + (kb ^ ((row&7)<<4)));
      }
      #pragma unroll
      for (int n=0;n<4;n++) {
        int row = wc*64 + n*16 + (lane&15);
        bF[n] = *(const half8*)(Bs + row*128 + (kb ^ ((row&7)<<4)));
      }
      #pragma unroll
      for (int m=0;m<4;m++)
        #pragma unroll
        for (int n=0;n<4;n++)
          acc[m][n] = __builtin_amdgcn_mfma_f32_16x16x32_f16(aF[m], bF[n], acc[m][n], 0,0,0);
    }
    __syncthreads();
  }
  // epilogue: C row r -> (b = r>>9, t = r&511); store [t][b][col]
  #pragma unroll
  for (int m=0;m<4;m++)
    #pragma unroll
    for (int n=0;n<4;n++)
      #pragma unroll
      for (int r=0;r<4;r++) {
        int row = r0 + wr*64 + m*16 + ((lane>>4)&3)*4 + r;
        int col = n0 + wc*64 + n*16 + (lane&15);
        GX0[((size_t)(row & 511)*NB + (row >> 9))*3072 + col] = (f16)acc[m][n][r];
      }
}

// ---------------- persistent pipelined recurrent kernel ----------------
// 256 WGs x 1024 thr. WG -> (layer = wg>>6, 16 cols = (wg&63)*16..). 16 waves:
// wave = (g: 0=gx-gemm 1=gh-gemm, mw: M-row-tile 0..3, kh: K-half 0..1).
// Per step: stage A(h_prev), A(hd), B(6 weight tiles) in 8 chunks of K=128 (reg->LDS,
// next chunk prefetched during MFMA); 48 MFMAs/wave; pairwise kh-reduce in LDS; gates.
__global__ __launch_bounds__(1024) void tsgru_k(
    const f16* __restrict__ WihH, const f16* __restrict__ WhhH,
    const float* __restrict__ bih, const float* __restrict__ bhh,
    const float* __restrict__ invTau, const float* __restrict__ dtp,
    const f16* __restrict__ GX0, f16* __restrict__ hseq, f16* __restrict__ hd,
    unsigned* arrive, float* __restrict__ out) {
  extern __shared__ char lds[];
  char* Ag = lds;                       // 16384: h_{l-1}[64][128] f16 swizzled
  char* Ah = lds + 16384;               // 16384: hd[64][128]
  char* Bt = lds + 32768;               // 24576: 6 tiles [16][128]
  float* PRE = (float*)(lds + 57344);   // [2][3][64][16] f32 = 24576

  const int tid = threadIdx.x, lane = tid & 63, wv = tid >> 6;
  const int g = wv >> 3, mw = (wv >> 1) & 3, kh = wv & 1;
  const int wg = blockIdx.x, layer = wg >> 6;
  const int col0 = (wg & 63) * 16;
  const bool mfmaValid = !(layer == 0 && g == 0);   // layer0 gx comes from GX0
  const int tlo = (layer == 0) ? 3 : 0;
  const int nB = (6 - tlo) * 256;

  const int gc = tid & 15, gb = tid >> 4;           // gate phase: (col, batch)
  const int gcol = col0 + gc;
  const float bihr = bih[layer*3072 + gcol], bihz = bih[layer*3072 + 1024 + gcol], bihn = bih[layer*3072 + 2048 + gcol];
  const float bhhr = bhh[layer*3072 + gcol], bhhz = bhh[layer*3072 + 1024 + gcol], bhhn = bhh[layer*3072 + 2048 + gcol];
  const float itau = invTau[layer*HID + gcol];

  const f16* Wg = WihH + (size_t)layer*3072*1024;
  const f16* Wh = WhhH + (size_t)layer*3072*1024;
  f16* hdL = hd + (size_t)layer*2*65536;
  unsigned* arrOwn = arrive + layer*TT;
  unsigned* arrUp  = arrive + (layer>0 ? (layer-1)*TT : 0);

  const int sArow = tid >> 4, sAc8 = (tid & 15)*8;
  const int sAoff = sArow*256 + ((sAc8*2) ^ ((sArow&7)<<4));

  for (int t = 0; t < TT; ++t) {
    // ---- wait: own group step t-1 complete; upstream step t published
    if (tid == 0) {
      long spins = 0;
      if (t > 0)
        while (__hip_atomic_load(arrOwn + (t-1), __ATOMIC_RELAXED, __HIP_MEMORY_SCOPE_AGENT) < 64u) {
          __builtin_amdgcn_s_sleep(2); if (++spins > (1L<<23)) break;
        }
      if (layer > 0)
        while (__hip_atomic_load(arrUp + t, __ATOMIC_RELAXED, __HIP_MEMORY_SCOPE_AGENT) < 64u) {
          __builtin_amdgcn_s_sleep(2); if (++spins > (1L<<24)) break;
        }
      __threadfence();   // acquire: invalidate L1 so cross-CU data is fresh
    }
    __syncthreads();

    const f16* Asrc = hseq + ((size_t)(layer-1)*TT + t)*65536;   // only deref'd when layer>0
    const f16* Hsrc = hdL + (size_t)(t & 1)*65536;

    f32x4 acc[3];
    acc[0] = (f32x4){0.f,0.f,0.f,0.f}; acc[1] = acc[0]; acc[2] = acc[0];

    half8 rAg, rAh, rB[2];
    // prologue load chunk 0
    if (layer > 0) rAg = *(const half8*)(Asrc + sArow*1024 + sAc8);
    rAh = *(const half8*)(Hsrc + sArow*1024 + sAc8);
    #pragma unroll
    for (int j=0;j<2;j++) {
      int id = tid + j*1024;
      if (id < nB) {
        int tile = tlo + (id >> 8), brow = (id >> 4) & 15, bc8 = (id & 15)*8;
        const f16* bs = (tile < 3) ? (Wg + (size_t)(tile*1024 + col0 + brow)*1024 + bc8)
                                   : (Wh + (size_t)((tile-3)*1024 + col0 + brow)*1024 + bc8);
        rB[j] = *(const half8*)bs;
      }
    }

    for (int kc = 0; kc < 8; ++kc) {
      // store staged regs -> LDS
      if (layer > 0) *(half8*)(Ag + sAoff) = rAg;
      *(half8*)(Ah + sAoff) = rAh;
      #pragma unroll
      for (int j=0;j<2;j++) {
        int id = tid + j*1024;
        if (id < nB) {
          int tile = tlo + (id >> 8), brow = (id >> 4) & 15, bc8 = (id & 15)*8;
          *(half8*)(Bt + tile*4096 + brow*256 + ((bc8*2) ^ ((brow&7)<<4))) = rB[j];
        }
      }
      __syncthreads();
      if (kc < 7) {   // prefetch next chunk during MFMA phase
        int k0 = (kc+1)*128;
        if (layer > 0) rAg = *(const half8*)(Asrc + sArow*1024 + k0 + sAc8);
        rAh = *(const half8*)(Hsrc + sArow*1024 + k0 + sAc8);
        #pragma unroll
        for (int j=0;j<2;j++) {
          int id = tid + j*1024;
          if (id < nB) {
            int tile = tlo + (id >> 8), brow = (id >> 4) & 15, bc8 = (id & 15)*8;
            const f16* bs = (tile < 3) ? (Wg + (size_t)(tile*1024 + col0 + brow)*1024 + k0 + bc8)
                                       : (Wh + (size_t)((tile-3)*1024 + col0 + brow)*1024 + k0 + bc8);
            rB[j] = *(const half8*)bs;
          }
        }
      }
      if (mfmaValid) {
        const char* Ab = g ? Ah : Ag;
        #pragma unroll
        for (int s = 0; s < 2; ++s) {
          int ks = kh*2 + s;
          int arow = mw*16 + (lane & 15);
          int kb = ks*64 + ((lane >> 4)&3)*16;
          half8 aF = *(const half8*)(Ab + arow*256 + (kb ^ ((arow&7)<<4)));
          int crow = lane & 15;
          #pragma unroll
          for (int q = 0; q < 3; ++q) {
            half8 bF = *(const half8*)(Bt + (g*3+q)*4096 + crow*256 + (kb ^ ((crow&7)<<4)));
            acc[q] = __builtin_amdgcn_mfma_f32_16x16x32_f16(aF, bF, acc[q], 0, 0, 0);
          }
        }
      }
      __syncthreads();
    }
    // ---- pairwise K-half reduction into PRE[g][gate][b][c]
    float* P = PRE + g*3072;
    if (mfmaValid && kh == 1) {
      #pragma unroll
      for (int q=0;q<3;q++)
        #pragma unroll
        for (int r=0;r<4;r++)
          P[q*1024 + (mw*16 + ((lane>>4)&3)*4 + r)*16 + (lane&15)] = acc[q][r];
    }
    __syncthreads();
    if (mfmaValid && kh == 0) {
      #pragma unroll
      for (int q=0;q<3;q++)
        #pragma unroll
        for (int r=0;r<4;r++)
          P[q*1024 + (mw*16 + ((lane>>4)&3)*4 + r)*16 + (lane&15)] += acc[q][r];
    }
    __syncthreads();
    // ---- gates: one h element per thread (b=gb, col=gcol), fp32 math
    {
      float xr, xz, xn;
      if (layer == 0) {
        const f16* gp = GX0 + ((size_t)t*NB + gb)*3072 + gcol;
        xr = (float)gp[0]; xz = (float)gp[1024]; xn = (float)gp[2048];
      } else {
        xr = PRE[gb*16 + gc]; xz = PRE[1024 + gb*16 + gc]; xn = PRE[2048 + gb*16 + gc];
      }
      float hr = PRE[3072 + gb*16 + gc];
      float hz = PRE[3072 + 1024 + gb*16 + gc];
      float hn = PRE[3072 + 2048 + gb*16 + gc];
      float hdv = (float)Hsrc[gb*HID + gcol];
      float rg = 1.f/(1.f + expf(-(xr + bihr + hr + bhhr)));
      float zg = 1.f/(1.f + expf(-(xz + bihz + hz + bhhz)));
      float ng = tanhf(xn + bihn + rg*(hn + bhhn));
      float hv = (1.f - zg)*ng + zg*hdv;
      if (layer < 3) hseq[((size_t)layer*TT + t)*65536 + gb*HID + gcol] = (f16)hv;
      else out[((size_t)gb*TT + t)*HID + gcol] = hv;
      if (t < TT-1) {
        float dk = expf(-dtp[gb*TT + t + 1] * itau);
        hdL[(size_t)((t+1)&1)*65536 + gb*HID + gcol] = (f16)(hv * dk);
      }
    }
    __syncthreads();
    if (tid == 0) {
      __threadfence();   // release: write back L2 so other XCDs see h/hd
      __hip_atomic_fetch_add(arrOwn + t, 1u, __ATOMIC_RELEASE, __HIP_MEMORY_SCOPE_AGENT);
    }
  }
}

extern "C" void kernel_launch(void* const* d_in, const int* in_sizes, int n_in,
                              void* d_out, int out_size, void* d_ws, size_t ws_size,
                              hipStream_t stream) {
  const float* x   = (const float*)d_in[0];
  const float* dtp = (const float*)d_in[1];
  const float* Wih = (const float*)d_in[2];
  const float* Whh = (const float*)d_in[3];
  const float* bih = (const float*)d_in[4];
  const float* bhh = (const float*)d_in[5];
  const float* tau = (const float*)d_in[6];
  float* out = (float*)d_out;
  char* ws = (char*)d_ws;

  // workspace layout (total 454,057,984 B)
  f16* WihH  = (f16*)(ws);                      // 4*3072*1024 f16
  f16* WhhH  = (f16*)(ws + 25165824);
  f16* GX0   = (f16*)(ws + 50331648);           // [512][64][3072] f16
  f16* hseq  = (f16*)(ws + 251658240);          // [3][512][64][1024] f16
  f16* hd    = (f16*)(ws + 452984832);          // [4][2][64][1024] f16
  float* invTau    = (float*)(ws + 454033408);  // [4][1024] f32
  unsigned* arrive = (unsigned*)(ws + 454049792); // [4][512] u32

  hipMemsetAsync(hd, 0, 1048576, stream);
  hipMemsetAsync(arrive, 0, 8192, stream);
  prep_k<<<2048, 256, 0, stream>>>(Wih, Whh, tau, WihH, WhhH, invTau);
  gx0_k<<<dim3(256, 24), 256, 0, stream>>>(x, WihH, GX0);
  hipFuncSetAttribute((const void*)tsgru_k, hipFuncAttributeMaxDynamicSharedMemorySize, 82432);
  // 82432 B LDS > 80KB -> hard 1 WG/CU, grid 256 = CU count -> all WGs co-resident
  tsgru_k<<<256, 1024, 82432, stream>>>(WihH, WhhH, bih, bhh, invTau, dtp, GX0, hseq, hd, arrive, out);
}

// Round 2
// 7504.632 us; speedup vs baseline: 2.1337x; 2.1337x over previous
//
#include <hip/hip_runtime.h>

typedef _Float16 f16;
typedef _Float16 half8 __attribute__((ext_vector_type(8)));
typedef float f32x4 __attribute__((ext_vector_type(4)));
typedef float f32x2 __attribute__((ext_vector_type(2)));

#define TT 512
#define HID 1024

__device__ __forceinline__ half8 cvt8(f32x4 lo, f32x4 hi) {
  half8 r;
  r[0]=(f16)lo[0]; r[1]=(f16)lo[1]; r[2]=(f16)lo[2]; r[3]=(f16)lo[3];
  r[4]=(f16)hi[0]; r[5]=(f16)hi[1]; r[6]=(f16)hi[2]; r[7]=(f16)hi[3];
  return r;
}
// coherent (device-scope) ops: write through / read past L2, never flush caches
__device__ __forceinline__ void st_sc_u32(unsigned* p, unsigned v) {
  asm volatile("global_store_dword %0, %1, off sc0 sc1" :: "v"(p), "v"(v) : "memory");
}
__device__ __forceinline__ void st_sc_f32x2(float* p, f32x2 v) {
  asm volatile("global_store_dwordx2 %0, %1, off sc0 sc1" :: "v"(p), "v"(v) : "memory");
}
__device__ __forceinline__ unsigned ld_sc_u32(const unsigned* p) {
  unsigned v;
  asm volatile("global_load_dword %0, %1, off sc0 sc1\n\ts_waitcnt vmcnt(0)"
               : "=v"(v) : "v"(p) : "memory");
  return v;
}

// x f32 -> f16 copy + flag init (sc stores so no dirty lines ever alias the flag lines)
__global__ void init_misc(const float* __restrict__ x, f16* __restrict__ xh,
                          unsigned* __restrict__ arrive) {
  size_t idx = (size_t)blockIdx.x*256 + threadIdx.x;
  size_t i = idx*8;
  f32x4 a = *(const f32x4*)(x+i);
  f32x4 b = *(const f32x4*)(x+i+4);
  *(half8*)(xh+i) = cvt8(a,b);
  if (idx < 131072) st_sc_u32(arrive + idx, 0u);
}

// Persistent pipelined TSGRU. 256 WGs x 512 thr (8 waves). WG=(layer=wg>>6, 16 cols).
// Wave (g = wv>>2, kq = wv&3): holds W[g][3 tiles][16 cols][K-slot kq of every 128-chunk]
// in 96 VGPRs for the whole run. Per step: 8 chunks of K=128 A-staging (double-buffered
// LDS, depth-2 reg prefetch, raw s_barrier + lgkmcnt-only so global loads stay in flight),
// 12 MFMAs/wave/chunk, LDS partial reduce over kq, fp32 gates, sc-store h + flag.
__global__ __launch_bounds__(512, 2) void tsgru_k(
    const float* __restrict__ dtp,
    const float* __restrict__ Wih, const float* __restrict__ Whh,
    const float* __restrict__ bih, const float* __restrict__ bhh,
    const float* __restrict__ tau, const f16* __restrict__ xh,
    f16* __restrict__ hseq, unsigned* __restrict__ arrive,
    float* __restrict__ out) {
  extern __shared__ char lds[];
  float* nitau_s = (float*)lds;                       // [1024] f32, persistent
  char* const bG[2] = { lds + 4096,  lds + 20480 };   // Ag dbuf [64][128] f16 swizzled
  char* const bH[2] = { lds + 36864, lds + 53248 };   // Ah (decayed h) dbuf
  float* PART = (float*)(lds + 4096);                 // [2g][4kq][3q][64][16] f32, aliases bufs

  const int tid = threadIdx.x, lane = tid & 63, wv = tid >> 6;
  const int g = wv >> 2, kq = wv & 3;
  const int wg = blockIdx.x, layer = wg >> 6, wgl = wg & 63;
  const int col0 = wgl * 16;

  for (int c = tid; c < HID; c += 512)
    nitau_s[c] = -1.0f / log1pf(expf(tau[layer*HID + c]));

  // ---- persistent weights in VGPRs (f32 source, convert inline; read once per launch)
  const float* Wsrc = (g == 0 ? Wih : Whh) + (size_t)layer*3072*HID;
  const int wrow = col0 + (lane & 15);
  const int kfrag = kq*32 + ((lane>>4)&3)*8;
  half8 bW[3][8];
  #pragma unroll
  for (int q=0;q<3;q++)
    #pragma unroll
    for (int kc=0;kc<8;kc++) {
      const float* p = Wsrc + (size_t)(q*HID + wrow)*HID + kc*128 + kfrag;
      bW[q][kc] = cvt8(*(const f32x4*)p, *(const f32x4*)(p+4));
    }

  // ---- gate-phase constants
  const int gb = tid >> 3, gc2 = (tid & 7) * 2;
  float bi0[2], bi1[2], bi2[2], bh0[2], bh1[2], bh2[2];
  #pragma unroll
  for (int e=0;e<2;e++) {
    bi0[e] = bih[layer*3072 + 0*HID + col0 + gc2 + e];
    bi1[e] = bih[layer*3072 + 1*HID + col0 + gc2 + e];
    bi2[e] = bih[layer*3072 + 2*HID + col0 + gc2 + e];
    bh0[e] = bhh[layer*3072 + 0*HID + col0 + gc2 + e];
    bh1[e] = bhh[layer*3072 + 1*HID + col0 + gc2 + e];
    bh2[e] = bhh[layer*3072 + 2*HID + col0 + gc2 + e];
  }

  const int srow0 = tid >> 4;          // staging rows: srow0 and srow0+32
  const int sc16 = tid & 15;
  const int so0 = srow0*256 + ((sc16*16) ^ ((srow0 & 7) << 4));
  const int so1 = so0 + 32*256;        // (srow0+32)&7 == srow0&7
  unsigned* const arrOwn = arrive + (size_t)layer*TT*64;
  const unsigned* const arrUp = arrive + (size_t)(layer>0 ? layer-1 : 0)*TT*64;

  __syncthreads();   // nitau ready

  for (int t = 0; t < TT; ++t) {
    // ---- point-to-point waits: own step t-1 (all 64 WGs), upstream step t
    if (wv == 0) {
      if (t > 0) {
        const unsigned* f = arrOwn + (size_t)(t-1)*64 + lane;
        int gd = 0;
        while (ld_sc_u32(f) == 0u) { __builtin_amdgcn_s_sleep(2); if (++gd > (1<<18)) break; }
      }
      if (layer > 0) {
        const unsigned* f = arrUp + (size_t)t*64 + lane;
        int gd = 0;
        while (ld_sc_u32(f) == 0u) { __builtin_amdgcn_s_sleep(2); if (++gd > (1<<18)) break; }
      }
    }
    __builtin_amdgcn_s_barrier();

    const float dt0 = dtp[srow0*TT + t];
    const float dt1 = dtp[(srow0+32)*TT + t];
    const f16* agB; size_t agS;
    if (layer == 0) { agB = xh + (size_t)t*HID; agS = (size_t)TT*HID; }
    else            { agB = hseq + ((size_t)(layer-1)*TT + t)*(size_t)65536; agS = (size_t)HID; }
    const f16* ahB = hseq + ((size_t)layer*TT + (t>0 ? t-1 : 0))*(size_t)65536;

    half8 rg[2][2], rh[2][2];

    auto loadChunk = [&](int kcL, half8 g2[2], half8 h2[2]) {
      const int cb = kcL*128 + sc16*8;
      g2[0] = *(const half8*)(agB + (size_t)srow0*agS + cb);
      g2[1] = *(const half8*)(agB + (size_t)(srow0+32)*agS + cb);
      if (t > 0) {
        h2[0] = *(const half8*)(ahB + srow0*HID + cb);
        h2[1] = *(const half8*)(ahB + (srow0+32)*HID + cb);
      }
    };
    auto storeChunk = [&](int kcL, half8 g2[2], half8 h2[2]) {
      const int par = kcL & 1;
      const int cb = kcL*128 + sc16*8;
      *(half8*)(bG[par] + so0) = g2[0];
      *(half8*)(bG[par] + so1) = g2[1];
      half8 d0, d1;
      if (t > 0) {   // decay applied on read: hd = h[t-1] * exp(dt * -1/softplus(tau))
        const f32x4 n0 = *(const f32x4*)(nitau_s + cb);
        const f32x4 n1 = *(const f32x4*)(nitau_s + cb + 4);
        #pragma unroll
        for (int i=0;i<4;i++) {
          d0[i]   = (f16)((float)h2[0][i]   * __expf(dt0*n0[i]));
          d0[4+i] = (f16)((float)h2[0][4+i] * __expf(dt0*n1[i]));
          d1[i]   = (f16)((float)h2[1][i]   * __expf(dt1*n0[i]));
          d1[4+i] = (f16)((float)h2[1][4+i] * __expf(dt1*n1[i]));
        }
      } else {
        #pragma unroll
        for (int i=0;i<8;i++) { d0[i]=(f16)0.f; d1[i]=(f16)0.f; }
      }
      *(half8*)(bH[par] + so0) = d0;
      *(half8*)(bH[par] + so1) = d1;
    };

    loadChunk(0, rg[0], rh[0]);
    loadChunk(1, rg[1], rh[1]);
    storeChunk(0, rg[0], rh[0]);
    asm volatile("s_waitcnt lgkmcnt(0)" ::: "memory");
    __builtin_amdgcn_s_barrier();

    f32x4 acc[4][3];
    #pragma unroll
    for (int m=0;m<4;m++)
      #pragma unroll
      for (int q=0;q<3;q++)
        acc[m][q] = (f32x4){0.f,0.f,0.f,0.f};

    const int kb = kq*64 + ((lane>>4)&3)*16;
    #pragma unroll
    for (int kc=0;kc<8;++kc) {
      if (kc < 6) loadChunk(kc+2, rg[kc&1], rh[kc&1]);   // depth-2 prefetch
      const char* Ab = g ? bH[kc&1] : bG[kc&1];
      #pragma unroll
      for (int m=0;m<4;m++) {
        const int arow = m*16 + (lane&15);
        const half8 aF = *(const half8*)(Ab + arow*256 + (kb ^ ((arow&7)<<4)));
        #pragma unroll
        for (int q=0;q<3;q++)
          acc[m][q] = __builtin_amdgcn_mfma_f32_16x16x32_f16(aF, bW[q][kc], acc[m][q], 0,0,0);
      }
      if (kc < 7) storeChunk(kc+1, rg[(kc+1)&1], rh[(kc+1)&1]);
      asm volatile("s_waitcnt lgkmcnt(0)" ::: "memory");   // LDS-only drain; vmem stays in flight
      __builtin_amdgcn_s_barrier();
    }

    // ---- partial sums (per (g,kq)) -> LDS
    {
      float* P = PART + (size_t)((g*4 + kq)*3)*1024 + (lane & 15);
      const int r0 = ((lane >> 4) & 3) * 4;
      #pragma unroll
      for (int q=0;q<3;q++)
        #pragma unroll
        for (int m=0;m<4;m++)
          #pragma unroll
          for (int r=0;r<4;r++)
            P[q*1024 + (m*16 + r0 + r)*16] = acc[m][q][r];
    }
    asm volatile("s_waitcnt lgkmcnt(0)" ::: "memory");
    __builtin_amdgcn_s_barrier();

    // ---- gates: thread -> (b = tid>>3, two cols), fp32 math
    {
      const float dtg = dtp[gb*TT + t];
      const f16* hp = hseq + ((size_t)layer*TT + (t>0 ? t-1 : 0))*(size_t)65536 + gb*HID + col0 + gc2;
      float hn2[2];
      #pragma unroll
      for (int e=0;e<2;e++) {
        const int c = gc2 + e;
        float sx0=0.f, sx1=0.f, sx2=0.f, sh0_=0.f, sh1_=0.f, sh2_=0.f;
        #pragma unroll
        for (int k2=0;k2<4;k2++) {
          const float* Pb = PART + (size_t)(k2*3)*1024 + gb*16 + c;
          sx0 += Pb[0]; sx1 += Pb[1024]; sx2 += Pb[2048];
          const float* Ph = PART + (size_t)((4+k2)*3)*1024 + gb*16 + c;
          sh0_ += Ph[0]; sh1_ += Ph[1024]; sh2_ += Ph[2048];
        }
        const float hprev = (t > 0) ? (float)hp[e] : 0.f;
        const float hdv = hprev * __expf(dtg * nitau_s[col0 + c]);
        const float rgt = 1.f/(1.f + __expf(-(sx0 + bi0[e] + sh0_ + bh0[e])));
        const float zgt = 1.f/(1.f + __expf(-(sx1 + bi1[e] + sh1_ + bh1[e])));
        const float ngt = tanhf(sx2 + bi2[e] + rgt*(sh2_ + bh2[e]));
        hn2[e] = (1.f - zgt)*ngt + zgt*hdv;
      }
      union { f16 h[2]; unsigned u; } pk;
      pk.h[0] = (f16)hn2[0]; pk.h[1] = (f16)hn2[1];
      st_sc_u32((unsigned*)(hseq + ((size_t)layer*TT + t)*(size_t)65536 + gb*HID + col0 + gc2), pk.u);
      if (layer == 3) {
        f32x2 v; v[0] = hn2[0]; v[1] = hn2[1];
        st_sc_f32x2(out + ((size_t)gb*TT + t)*HID + col0 + gc2, v);
      }
    }
    asm volatile("s_waitcnt vmcnt(0) lgkmcnt(0)" ::: "memory");  // all sc stores at coherent point
    __builtin_amdgcn_s_barrier();
    if (tid == 0) st_sc_u32(arrOwn + (size_t)t*64 + wgl, 1u);
  }
}

extern "C" void kernel_launch(void* const* d_in, const int* in_sizes, int n_in,
                              void* d_out, int out_size, void* d_ws, size_t ws_size,
                              hipStream_t stream) {
  const float* x   = (const float*)d_in[0];
  const float* dtp = (const float*)d_in[1];
  const float* Wih = (const float*)d_in[2];
  const float* Whh = (const float*)d_in[3];
  const float* bih = (const float*)d_in[4];
  const float* bhh = (const float*)d_in[5];
  const float* tau = (const float*)d_in[6];
  float* out = (float*)d_out;
  char* ws = (char*)d_ws;

  // workspace: xh [64][512][1024] f16 (67,108,864) | hseq [4][512][64][1024] f16
  // (268,435,456) | arrive [4][512][64] u32 (524,288)  -> total 336,068,608 B
  f16* xh = (f16*)ws;
  f16* hseq = (f16*)(ws + 67108864);
  unsigned* arrive = (unsigned*)(ws + 67108864 + 268435456);

  init_misc<<<16384, 256, 0, stream>>>(x, xh, arrive);
  const int ldsBytes = 102400;   // 4K nitau + 96K (A dbufs aliased under PART)
  hipFuncSetAttribute((const void*)tsgru_k, hipFuncAttributeMaxDynamicSharedMemorySize, ldsBytes);
  // 102400 B LDS -> hard 1 WG/CU; grid 256 = CU count -> all WGs co-resident
  tsgru_k<<<256, 512, ldsBytes, stream>>>(dtp, Wih, Whh, bih, bhh, tau, xh, hseq, arrive, out);
}